// Round 4
// baseline (171.594 us; speedup 1.0000x reference)
//
#include <hip/hip_runtime.h>

// Problem constants (from reference)
#define S 4
#define T 512
#define B 16
#define D 512
#define L (T * T)  // placeholder guard (unused)
#undef L
#define L (T * D)            // 262144 floats per (b,s) signal
#define SSTRIDE (T * B * D)  // 4194304 floats between sources (both tensors)

#define THREADS 128   // 2 waves per block
#define BLOCKS 1024   // 2048 waves total = 16 b * 128 segments
#define SEGS_PER_B 128
#define SEG_FLOATS (L / SEGS_PER_B)  // 2048 floats per wave per stream
#define TILE_F 256                   // floats staged per stream per iter (64 lanes * 4)
#define ITERS (SEG_FLOATS / TILE_F)  // 8

// s_waitcnt immediate encodings (gfx9): simm[3:0]=vmcnt lo, simm[15:14]=vmcnt hi,
// simm[6:4]=expcnt, simm[11:8]=lgkmcnt. Leave exp/lgkm at max (don't wait).
#define WAITCNT_VM8 0x0F78  // vmcnt(8)
#define WAITCNT_VM0 0x0F70  // vmcnt(0)

__device__ __forceinline__ void dma16(const float* gp, float* lp) {
  __builtin_amdgcn_global_load_lds(
      (const __attribute__((address_space(1))) void*)gp,
      (__attribute__((address_space(3))) void*)lp, 16, 0, 0);
}

// preds: [S,T,B,D] -> idx = s*SSTRIDE + t*(B*D) + b*D + d
// gts:   [S,B,T,D] -> idx = s*SSTRIDE + b*L + (t*D + d)
// ws per batch b (24 floats): [0..15] dot[sp*4+sg], [16..19] pn[s], [20..23] gn[s]

__global__ __launch_bounds__(THREADS) void partial_kernel(
    const float* __restrict__ preds, const float* __restrict__ gts,
    float* __restrict__ ws) {
  // LDS: [wave][buf][stream][TILE_F] = 2*2*8*256*4B = 32 KB -> 4 blocks/CU
  __shared__ float tile[2][2][8][TILE_F];

  const int tid = threadIdx.x;
  const int lane = tid & 63;
  const int w = tid >> 6;

  const int gw = blockIdx.x * 2 + w;  // global wave id in [0, 2048)
  const int b = gw >> 7;              // batch
  const int seg = gw & (SEGS_PER_B - 1);

  float dot[16], pn[4], gn[4];
#pragma unroll
  for (int k = 0; k < 16; k++) dot[k] = 0.f;
#pragma unroll
  for (int k = 0; k < 4; k++) { pn[k] = 0.f; gn[k] = 0.f; }

  // Issue iteration 'it' into buffer 'buf' (8 x 1KB wave-DMAs, no VGPR return)
  auto issue = [&](int it, int buf) {
    const int fb = seg * SEG_FLOATS + it * TILE_F;  // float index within L
    const int t = fb >> 9;                          // fb / 512
    const int d = fb & 511;                         // aligned to 256
    const float* pg = preds + (size_t)t * (B * D) + (size_t)b * D + d + lane * 4;
    const float* gg = gts + (size_t)b * L + fb + lane * 4;
#pragma unroll
    for (int s = 0; s < 4; s++) {
      dma16(pg + (size_t)s * SSTRIDE, &tile[w][buf][s][0]);
      dma16(gg + (size_t)s * SSTRIDE, &tile[w][buf][4 + s][0]);
    }
  };

  issue(0, 0);
#pragma unroll
  for (int it = 0; it < ITERS; ++it) {
    if (it + 1 < ITERS) {
      issue(it + 1, (it + 1) & 1);
      __builtin_amdgcn_s_waitcnt(WAITCNT_VM8);  // oldest 8 (current buf) done
    } else {
      __builtin_amdgcn_s_waitcnt(WAITCNT_VM0);
    }
    const int cb = it & 1;
    float4 p[4], g[4];
#pragma unroll
    for (int s = 0; s < 4; s++)
      p[s] = *reinterpret_cast<const float4*>(&tile[w][cb][s][lane * 4]);
#pragma unroll
    for (int s = 0; s < 4; s++)
      g[s] = *reinterpret_cast<const float4*>(&tile[w][cb][4 + s][lane * 4]);

#pragma unroll
    for (int s = 0; s < 4; s++) {
      pn[s] += p[s].x * p[s].x + p[s].y * p[s].y + p[s].z * p[s].z + p[s].w * p[s].w;
      gn[s] += g[s].x * g[s].x + g[s].y * g[s].y + g[s].z * g[s].z + g[s].w * g[s].w;
    }
#pragma unroll
    for (int sp = 0; sp < 4; sp++) {
#pragma unroll
      for (int sg = 0; sg < 4; sg++) {
        dot[sp * 4 + sg] += p[sp].x * g[sg].x + p[sp].y * g[sg].y +
                            p[sp].z * g[sg].z + p[sp].w * g[sg].w;
      }
    }
  }

  // Per-wave reduction (wave owns a single b -> no cross-wave combine needed).
#pragma unroll
  for (int k = 0; k < 24; k++) {
    float v = (k < 16) ? dot[k] : ((k < 20) ? pn[k - 16] : gn[k - 20]);
#pragma unroll
    for (int off = 32; off > 0; off >>= 1) v += __shfl_down(v, off, 64);
    if (lane == 0) tile[w][0][0][k] = v;  // tile is dead; reuse as scratch
  }
  // Same-wave DS ops are in-order; compiler inserts lgkmcnt before use.
  if (lane < 24) atomicAdd(&ws[b * 24 + lane], tile[w][0][0][lane]);
}

__global__ __launch_bounds__(64) void finalize_kernel(const float* __restrict__ ws,
                                                      float* __restrict__ out) {
  const int tid = threadIdx.x;
  float local = 0.f;
  if (tid < B) {
    const float* w = ws + tid * 24;
    float dist[4][4], dcur[4][4];
#pragma unroll
    for (int r = 0; r < 4; r++) {
#pragma unroll
      for (int c = 0; c < 4; c++) {
        float d2 = w[16 + r] + w[20 + c] - 2.0f * w[r * 4 + c];
        float dd = sqrtf(fmaxf(d2, 0.0f));
        dist[r][c] = dd;
        dcur[r][c] = dd;
      }
    }
    int match[4] = {0, 0, 0, 0};
    for (int it = 0; it < 4; ++it) {
      // row-major first-occurrence argmin (matches jnp.argmin on flattened)
      float best = INFINITY;
      int bm = 0;
      for (int r = 0; r < 4; r++)
        for (int c = 0; c < 4; c++) {
          float v = dcur[r][c];
          if (v < best) { best = v; bm = r * 4 + c; }
        }
      const int r = bm >> 2, c = bm & 3;
      match[r] = c;
      for (int k = 0; k < 4; k++) { dcur[r][k] = INFINITY; dcur[k][c] = INFINITY; }
    }
#pragma unroll
    for (int r = 0; r < 4; r++) local += dist[r][match[r]];
  }
#pragma unroll
  for (int off = 32; off > 0; off >>= 1) local += __shfl_down(local, off, 64);
  if (tid == 0) out[0] = local;
}

extern "C" void kernel_launch(void* const* d_in, const int* in_sizes, int n_in,
                              void* d_out, int out_size, void* d_ws, size_t ws_size,
                              hipStream_t stream) {
  const float* preds = (const float*)d_in[0];  // [S,T,B,D]
  const float* gts = (const float*)d_in[1];    // [S,B,T,D]
  float* ws = (float*)d_ws;                    // B*24 floats of accumulators

  hipMemsetAsync(d_ws, 0, B * 24 * sizeof(float), stream);
  partial_kernel<<<dim3(BLOCKS), dim3(THREADS), 0, stream>>>(preds, gts, ws);
  finalize_kernel<<<dim3(1), dim3(64), 0, stream>>>(ws, (float*)d_out);
}

// Round 5
// 159.952 us; speedup vs baseline: 1.0728x; 1.0728x over previous
//
#include <hip/hip_runtime.h>

// Problem constants (from reference)
#define S 4
#define T 512
#define B 16
#define D 512
#define L (T * D)            // 262144 floats per (b,s) signal
#define SSTRIDE (T * B * D)  // 4194304 floats between sources (both tensors)

#define CHUNKS 64
#define THREADS 256
// Per stream per block: L/CHUNKS = 4096 floats (16 KB).
// Per iter: 256 threads x 8 floats (2x float4, 32B contiguous per lane) = 2048 floats.
#define ITERS 2

// preds: [S,T,B,D] -> idx = s*SSTRIDE + t*(B*D) + b*D + d
// gts:   [S,B,T,D] -> idx = s*SSTRIDE + b*L + (t*D + d)
//
// ws layout per batch b (24 floats): [0..15] dot[sp*4+sg], [16..19] pn[s], [20..23] gn[s]

__global__ __launch_bounds__(THREADS) void partial_kernel(
    const float* __restrict__ preds, const float* __restrict__ gts,
    float* __restrict__ ws) {
  const int b = blockIdx.x & (B - 1);   // b fast: 16 consecutive blocks cover a
  const int chunk = blockIdx.x >> 4;    // contiguous 32KB preds row-span per t
  const int tid = threadIdx.x;

  float dot[16], pn[4], gn[4];
#pragma unroll
  for (int k = 0; k < 16; k++) dot[k] = 0.f;
#pragma unroll
  for (int k = 0; k < 4; k++) { pn[k] = 0.f; gn[k] = 0.f; }

#pragma unroll
  for (int it = 0; it < ITERS; ++it) {
    // element index within L; each lane owns 8 consecutive floats (32 B)
    const int i = chunk * (L / CHUNKS) + it * (THREADS * 8) + tid * 8;
    const int t = i >> 9;  // i / 512  (8 floats never cross a d-row)
    const int d = i & 511;

    const float* pbase = preds + (size_t)t * (B * D) + (size_t)b * D + d;
    const float* gbase = gts + (size_t)b * L + i;

    float4 p[4][2], g[4][2];
#pragma unroll
    for (int s = 0; s < 4; s++) {
      const float4* pp = reinterpret_cast<const float4*>(pbase + (size_t)s * SSTRIDE);
      p[s][0] = pp[0];
      p[s][1] = pp[1];
    }
#pragma unroll
    for (int s = 0; s < 4; s++) {
      const float4* gp = reinterpret_cast<const float4*>(gbase + (size_t)s * SSTRIDE);
      g[s][0] = gp[0];
      g[s][1] = gp[1];
    }

#pragma unroll
    for (int h = 0; h < 2; h++) {
#pragma unroll
      for (int s = 0; s < 4; s++) {
        const float4 pv = p[s][h];
        const float4 gv = g[s][h];
        pn[s] += pv.x * pv.x + pv.y * pv.y + pv.z * pv.z + pv.w * pv.w;
        gn[s] += gv.x * gv.x + gv.y * gv.y + gv.z * gv.z + gv.w * gv.w;
      }
#pragma unroll
      for (int sp = 0; sp < 4; sp++) {
        const float4 pv = p[sp][h];
#pragma unroll
        for (int sg = 0; sg < 4; sg++) {
          const float4 gv = g[sg][h];
          dot[sp * 4 + sg] += pv.x * gv.x + pv.y * gv.y + pv.z * gv.z + pv.w * gv.w;
        }
      }
    }
  }

  // Block reduction: wave shuffle -> LDS -> 24 atomics
  __shared__ float red[24][4];
  const int lane = tid & 63;
  const int wave = tid >> 6;
#pragma unroll
  for (int k = 0; k < 24; k++) {
    float v = (k < 16) ? dot[k] : ((k < 20) ? pn[k - 16] : gn[k - 20]);
#pragma unroll
    for (int off = 32; off > 0; off >>= 1) v += __shfl_down(v, off, 64);
    if (lane == 0) red[k][wave] = v;
  }
  __syncthreads();
  if (tid < 24) {
    float s = red[tid][0] + red[tid][1] + red[tid][2] + red[tid][3];
    atomicAdd(&ws[b * 24 + tid], s);
  }
}

__global__ __launch_bounds__(64) void finalize_kernel(const float* __restrict__ ws,
                                                      float* __restrict__ out) {
  const int tid = threadIdx.x;
  float local = 0.f;
  if (tid < B) {
    const float* w = ws + tid * 24;
    float dist[4][4], dcur[4][4];
#pragma unroll
    for (int r = 0; r < 4; r++) {
#pragma unroll
      for (int c = 0; c < 4; c++) {
        float d2 = w[16 + r] + w[20 + c] - 2.0f * w[r * 4 + c];
        float dd = sqrtf(fmaxf(d2, 0.0f));
        dist[r][c] = dd;
        dcur[r][c] = dd;
      }
    }
    int match[4] = {0, 0, 0, 0};
    for (int it = 0; it < 4; ++it) {
      // row-major first-occurrence argmin (matches jnp.argmin on flattened)
      float best = INFINITY;
      int bm = 0;
      for (int r = 0; r < 4; r++)
        for (int c = 0; c < 4; c++) {
          float v = dcur[r][c];
          if (v < best) { best = v; bm = r * 4 + c; }
        }
      const int r = bm >> 2, c = bm & 3;
      match[r] = c;
      for (int k = 0; k < 4; k++) { dcur[r][k] = INFINITY; dcur[k][c] = INFINITY; }
    }
#pragma unroll
    for (int r = 0; r < 4; r++) local += dist[r][match[r]];
  }
#pragma unroll
  for (int off = 32; off > 0; off >>= 1) local += __shfl_down(local, off, 64);
  if (tid == 0) out[0] = local;
}

extern "C" void kernel_launch(void* const* d_in, const int* in_sizes, int n_in,
                              void* d_out, int out_size, void* d_ws, size_t ws_size,
                              hipStream_t stream) {
  const float* preds = (const float*)d_in[0];  // [S,T,B,D]
  const float* gts = (const float*)d_in[1];    // [S,B,T,D]
  float* ws = (float*)d_ws;                    // B*24 floats of accumulators

  hipMemsetAsync(d_ws, 0, B * 24 * sizeof(float), stream);
  partial_kernel<<<dim3(B * CHUNKS), dim3(THREADS), 0, stream>>>(preds, gts, ws);
  finalize_kernel<<<dim3(1), dim3(64), 0, stream>>>(ws, (float*)d_out);
}